// Round 2
// baseline (47.867 us; speedup 1.0000x reference)
//
#include <hip/hip_runtime.h>

#define L 24
#define W 24
#define H 24
#define C 32
#define K 5
#define P 2
#define ZP (H + 2*P)          // 28  padded z-extent
#define YB 4                  // y values per block
#define YW (YB + 2*P)         // 8   padded y-window
#define SLAB (K*YW*ZP)        // 5*8*28 = 1120 floats
#define JOUT (K*K*K)          // 125
#define ROWOUT (H*JOUT)       // 3000 floats per (c,x,y)
#define NV4 (YB*ROWOUT/4)     // 3000 float4 per block

typedef float f32x4 __attribute__((ext_vector_type(4)));

__global__ __launch_bounds__(256) void selfcorr_kernel(const float* __restrict__ q,
                                                       float* __restrict__ out) {
    __shared__ float s_nb[SLAB];   // [xx][yy][zz] zero-padded slab
    __shared__ int   s_t[JOUT];    // t[j] = (k0*YW + k1)*ZP + k2

    const int blk = blockIdx.x;               // (c*24 + x)*(24/YB) + yb
    const int yb = blk % (W / YB);
    const int cx = blk / (W / YB);
    const int x  = cx % L;
    const int c  = cx / L;
    const int y0 = yb * YB;
    const int tid = threadIdx.x;

    // Stage zero-padded slab: s_nb[(xx*YW+yy)*ZP+zz] = q[c, x+xx-2, y0+yy-2, zz-2]
    for (int i = tid; i < SLAB; i += 256) {
        int xx = i / (YW * ZP);
        int r  = i - xx * (YW * ZP);
        int yy = r / ZP;
        int zz = r - yy * ZP;
        int gx = x + xx - P;
        int gy = y0 + yy - P;
        int gz = zz - P;
        float v = 0.0f;
        if ((unsigned)gx < (unsigned)L && (unsigned)gy < (unsigned)W && (unsigned)gz < (unsigned)H)
            v = q[((c * L + gx) * W + gy) * H + gz];
        s_nb[i] = v;
    }
    if (tid < JOUT) {
        int k0 = tid / 25;
        int r  = tid - k0 * 25;
        int k1 = r / 5;
        int k2 = r - k1 * 5;
        s_t[tid] = (k0 * YW + k1) * ZP + k2;
    }
    __syncthreads();

    float* outp = out + (size_t)((c * L + x) * W + y0) * ROWOUT;
    const int C0 = (P * YW + P) * ZP + P;   // (2*8+2)*28+2 = 506

    for (int e4 = tid; e4 < NV4; e4 += 256) {
        int e = e4 * 4;
        f32x4 v;
        #pragma unroll
        for (int u = 0; u < 4; ++u) {
            int ee = e + u;
            int yl = ee / ROWOUT;
            int r1 = ee - yl * ROWOUT;
            int z  = r1 / JOUT;
            int j  = r1 - z * JOUT;
            int o  = yl * ZP + z;
            float p = s_nb[C0 + o] * s_nb[s_t[j] + o];
            v[u] = fmaxf(p, 0.0f);
        }
        __builtin_nontemporal_store(v, reinterpret_cast<f32x4*>(outp + e));
    }
}

extern "C" void kernel_launch(void* const* d_in, const int* in_sizes, int n_in,
                              void* d_out, int out_size, void* d_ws, size_t ws_size,
                              hipStream_t stream) {
    const float* q = (const float*)d_in[0];
    float* out = (float*)d_out;
    const int nblk = C * L * (W / YB);   // 4608
    selfcorr_kernel<<<nblk, 256, 0, stream>>>(q, out);
}

// Round 3
// 41.296 us; speedup vs baseline: 1.1591x; 1.1591x over previous
//
#include <hip/hip_runtime.h>

#define L 24
#define W 24
#define H 24
#define C 32
#define K 5
#define P 2
#define ZP (H + 2*P)        // 28  padded z-extent
#define NBSZ (K*K*ZP)       // 700 floats per block slab
#define JOUT (K*K*K)        // 125 offsets
#define PER_BLK (H*JOUT)    // 3000 output floats per (c,x,y)
#define NV4 (PER_BLK/4)     // 750 float4 per block

typedef float f32x4 __attribute__((ext_vector_type(4)));

__global__ __launch_bounds__(256) void selfcorr_kernel(const float* __restrict__ q,
                                                       float* __restrict__ out) {
    __shared__ float s_nb[NBSZ];   // [k0*5+k1][zz]  zero-padded neighbor rows
    __shared__ int   s_t[JOUT];    // t[j] = (k0*5+k1)*28 + k2
    __shared__ int   s_zj[NV4];    // packed (z<<8)|j for each float4 slot

    const int blk = blockIdx.x;            // (c*24 + x)*24 + y
    const int y  = blk % W;
    const int cx = blk / W;
    const int x  = cx % L;
    const int c  = cx / L;
    const int tid = threadIdx.x;

    // Stage the 5x5x28 zero-padded slab: s_nb[kk*28+zz] = q[c, x+kk/5-2, y+kk%5-2, zz-2]
    for (int i = tid; i < NBSZ; i += 256) {
        int kk = i / ZP;
        int zz = i - kk * ZP;
        int gx = x + kk / K - P;
        int gy = y + kk % K - P;
        int gz = zz - P;
        float v = 0.0f;
        if ((unsigned)gx < (unsigned)L && (unsigned)gy < (unsigned)W && (unsigned)gz < (unsigned)H)
            v = q[((c * L + gx) * W + gy) * H + gz];
        s_nb[i] = v;
    }
    if (tid < JOUT) {
        int k0 = tid / 25;
        int r  = tid - k0 * 25;
        int k1 = r / 5;
        int k2 = r - k1 * 5;
        s_t[tid] = (k0 * K + k1) * ZP + k2;
    }
    // Decode table: divides live here (prologue), not in the hot loop.
    for (int i = tid; i < NV4; i += 256) {
        int e = i * 4;
        int z = e / JOUT;
        int j = e - z * JOUT;
        s_zj[i] = (z << 8) | j;
    }
    __syncthreads();

    float* outp = out + (size_t)blk * PER_BLK;
    const int CENTER = (P * K + P) * ZP + P;   // 12*28+2 = 338

    #pragma unroll
    for (int i = 0; i < 3; ++i) {
        int e4 = i * 256 + tid;
        if (e4 < NV4) {
            int zj = s_zj[e4];
            int z0 = zj >> 8;
            int j0 = zj & 255;
            // z changes at most once inside a float4 (when j wraps past 125).
            float c0 = s_nb[CENTER + z0];
            float c1 = s_nb[CENTER + z0 + 1];   // in-bounds: CENTER+24 < 700
            f32x4 v;
            #pragma unroll
            for (int u = 0; u < 4; ++u) {
                int ju = j0 + u;
                bool wrap = (ju >= JOUT);
                int jj = wrap ? ju - JOUT : ju;
                int zz = wrap ? z0 + 1 : z0;
                float cc = wrap ? c1 : c0;
                float p = cc * s_nb[s_t[jj] + zz];
                v[u] = fmaxf(p, 0.0f);
            }
            *reinterpret_cast<f32x4*>(outp + e4 * 4) = v;
        }
    }
}

extern "C" void kernel_launch(void* const* d_in, const int* in_sizes, int n_in,
                              void* d_out, int out_size, void* d_ws, size_t ws_size,
                              hipStream_t stream) {
    const float* q = (const float*)d_in[0];
    float* out = (float*)d_out;
    const int nblk = C * L * W;   // 18432
    selfcorr_kernel<<<nblk, 256, 0, stream>>>(q, out);
}